// Round 1
// baseline (2932.586 us; speedup 1.0000x reference)
//
#include <hip/hip_runtime.h>

#define TT 4096      // tokens (B*S)
#define DM 1024      // d_model
#define HH 4096      // hidden
#define NE 8         // experts
#define NSLOT (TT*2) // total routed slots (always T*K)
#define BK 16
#define MAXTILES 136 // 8192/64 + 8 partial tiles

// ---------- bf16 helpers (raw ushort, RNE) ----------
__device__ __forceinline__ unsigned short f2bs(float f) {
  unsigned u = __float_as_uint(f);
  u += 0x7fffu + ((u >> 16) & 1u);
  return (unsigned short)(u >> 16);
}
__device__ __forceinline__ float bs2f(unsigned short s) {
  return __uint_as_float(((unsigned)s) << 16);
}

// ---------- K1: gating (logits, top-2, softmax, aux sums, counts) ----------
__global__ __launch_bounds__(256) void k_gate(
    const float* __restrict__ x, const float* __restrict__ w_gate,
    int* __restrict__ counts, float* __restrict__ gsum, float* __restrict__ psum,
    int* __restrict__ gidx, float* __restrict__ gval) {
  __shared__ float wg[NE * DM];
  __shared__ float bg[NE]; __shared__ float bp[NE]; __shared__ int bc[NE];
  int tid = threadIdx.x;
  for (int i = tid; i < NE * DM; i += 256) wg[i] = w_gate[i];
  if (tid < NE) { bg[tid] = 0.f; bp[tid] = 0.f; bc[tid] = 0; }
  __syncthreads();
  int wave = tid >> 6, lane = tid & 63;
  for (int it = 0; it < 4; ++it) {
    int t = blockIdx.x * 16 + wave * 4 + it;
    const float* xr = x + (size_t)t * DM;
    float s[NE];
#pragma unroll
    for (int e = 0; e < NE; ++e) s[e] = 0.f;
    for (int d = lane; d < DM; d += 64) {
      float xv = xr[d];
#pragma unroll
      for (int e = 0; e < NE; ++e) s[e] += xv * wg[e * DM + d];
    }
#pragma unroll
    for (int e = 0; e < NE; ++e) {
      float v = s[e];
      v += __shfl_down(v, 32); v += __shfl_down(v, 16); v += __shfl_down(v, 8);
      v += __shfl_down(v, 4);  v += __shfl_down(v, 2);  v += __shfl_down(v, 1);
      s[e] = v;
    }
    if (lane == 0) {
      // top-2 (stable, descending — matches lax.top_k)
      int e1 = 0; float v1 = s[0];
      for (int e = 1; e < NE; ++e) if (s[e] > v1) { v1 = s[e]; e1 = e; }
      int e2 = -1; float v2 = -1e30f;
      for (int e = 0; e < NE; ++e) if (e != e1 && s[e] > v2) { v2 = s[e]; e2 = e; }
      float g1 = 1.f / (1.f + __expf(v2 - v1));
      float g2 = 1.f - g1;
      float psm = 0.f, p[NE];
      for (int e = 0; e < NE; ++e) { p[e] = __expf(s[e] - v1); psm += p[e]; }
      float inv = 1.f / psm;
      atomicAdd(&bg[e1], g1); atomicAdd(&bg[e2], g2);
      for (int e = 0; e < NE; ++e) atomicAdd(&bp[e], p[e] * inv);
      atomicAdd(&bc[e1], 1); atomicAdd(&bc[e2], 1);
      gidx[t * 2] = e1; gidx[t * 2 + 1] = e2;
      gval[t * 2] = g1; gval[t * 2 + 1] = g2;
    }
  }
  __syncthreads();
  if (tid < NE) {
    atomicAdd(&counts[tid], bc[tid]);
    atomicAdd(&gsum[tid], bg[tid]);
    atomicAdd(&psum[tid], bp[tid]);
  }
}

// ---------- K2: plan (prefix sum, tile table, aux loss) ----------
__global__ void k_plan(const int* __restrict__ counts, const float* __restrict__ gsum,
                       const float* __restrict__ psum, int* __restrict__ bases,
                       int* __restrict__ ntiles, int* __restrict__ tile_e,
                       int* __restrict__ tile_s0, int* __restrict__ tile_n,
                       float* __restrict__ aux_out) {
  if (threadIdx.x != 0 || blockIdx.x != 0) return;
  int base = 0, nt = 0;
  for (int e = 0; e < NE; ++e) {
    bases[e] = base;
    int c = counts[e];
    for (int s = 0; s < c; s += 64) {
      tile_e[nt] = e; tile_s0[nt] = base + s;
      tile_n[nt] = (c - s < 64) ? (c - s) : 64; ++nt;
    }
    base += c;
  }
  *ntiles = nt;
  float aux = 0.f;
  for (int e = 0; e < NE; ++e)
    aux += (gsum[e] / (float)TT) * (psum[e] / (float)TT);
  *aux_out = aux * (float)NE;
}

// ---------- K3: scatter tokens into expert-grouped slot lists ----------
__global__ __launch_bounds__(256) void k_scatter(
    const int* __restrict__ gidx, const int* __restrict__ bases,
    int* __restrict__ cursor, int* __restrict__ stok, int* __restrict__ t2s) {
  int t = blockIdx.x * 256 + threadIdx.x;
#pragma unroll
  for (int k = 0; k < 2; ++k) {
    int e = gidx[t * 2 + k];
    int pos = atomicAdd(&cursor[e], 1);
    int slot = bases[e] + pos;
    stok[slot] = t;
    t2s[t * 2 + k] = slot;
  }
}

// ---------- K4: grouped GEMM1 — h = silu(x Wg^T) * (x Wu^T), store bf16 ----------
__global__ __launch_bounds__(256) void k_ffn1(
    const float* __restrict__ x, const float* __restrict__ w_g, const float* __restrict__ w_u,
    const int* __restrict__ ntiles, const int* __restrict__ tile_e,
    const int* __restrict__ tile_s0, const int* __restrict__ tile_n,
    const int* __restrict__ stok, unsigned short* __restrict__ hbuf) {
  int mt = blockIdx.x;
  if (mt >= *ntiles) return;
  int e = tile_e[mt], s0 = tile_s0[mt], nrows = tile_n[mt];
  int n0 = blockIdx.y * 64;
  __shared__ float As[BK][68];
  __shared__ float Bgs[BK][68];
  __shared__ float Bus[BK][68];
  __shared__ int tokb[64];
  int tid = threadIdx.x;
  if (tid < 64) tokb[tid] = (tid < nrows) ? stok[s0 + tid] : 0;
  __syncthreads();
  int row = tid >> 2, kq = (tid & 3) << 2;
  int tok = tokb[row];
  const float* ap = x + (size_t)tok * DM + kq;
  const float* gp = w_g + ((size_t)e * HH + (size_t)(n0 + row)) * DM + kq;
  const float* up = w_u + ((size_t)e * HH + (size_t)(n0 + row)) * DM + kq;
  int ty = tid >> 4, tx = tid & 15;
  float accg[4][4] = {}, accu[4][4] = {};
  for (int k0 = 0; k0 < DM; k0 += BK) {
    float4 av = *(const float4*)(ap + k0);
    float4 gv = *(const float4*)(gp + k0);
    float4 uv = *(const float4*)(up + k0);
    __syncthreads();
    As[kq + 0][row] = av.x; As[kq + 1][row] = av.y; As[kq + 2][row] = av.z; As[kq + 3][row] = av.w;
    Bgs[kq + 0][row] = gv.x; Bgs[kq + 1][row] = gv.y; Bgs[kq + 2][row] = gv.z; Bgs[kq + 3][row] = gv.w;
    Bus[kq + 0][row] = uv.x; Bus[kq + 1][row] = uv.y; Bus[kq + 2][row] = uv.z; Bus[kq + 3][row] = uv.w;
    __syncthreads();
#pragma unroll
    for (int kk = 0; kk < BK; ++kk) {
      float4 a4 = *(const float4*)&As[kk][ty * 4];
      float4 g4 = *(const float4*)&Bgs[kk][tx * 4];
      float4 u4 = *(const float4*)&Bus[kk][tx * 4];
      float aa[4] = {a4.x, a4.y, a4.z, a4.w};
      float gg[4] = {g4.x, g4.y, g4.z, g4.w};
      float uu[4] = {u4.x, u4.y, u4.z, u4.w};
#pragma unroll
      for (int i = 0; i < 4; ++i)
#pragma unroll
        for (int j = 0; j < 4; ++j) {
          accg[i][j] += aa[i] * gg[j];
          accu[i][j] += aa[i] * uu[j];
        }
    }
  }
#pragma unroll
  for (int i = 0; i < 4; ++i) {
    int r = ty * 4 + i;
    if (r < nrows) {
      ushort4 pk;
      float a0, b0, h;
      a0 = accg[i][0]; b0 = accu[i][0]; h = a0 / (1.f + __expf(-a0)) * b0; pk.x = f2bs(h);
      a0 = accg[i][1]; b0 = accu[i][1]; h = a0 / (1.f + __expf(-a0)) * b0; pk.y = f2bs(h);
      a0 = accg[i][2]; b0 = accu[i][2]; h = a0 / (1.f + __expf(-a0)) * b0; pk.z = f2bs(h);
      a0 = accg[i][3]; b0 = accu[i][3]; h = a0 / (1.f + __expf(-a0)) * b0; pk.w = f2bs(h);
      *(ushort4*)(hbuf + ((size_t)(s0 + r) * HH + n0 + tx * 4)) = pk;
    }
  }
}

// ---------- K5: grouped GEMM2 — y = h Wd^T, store bf16 per-slot ----------
__global__ __launch_bounds__(256) void k_ffn2(
    const unsigned short* __restrict__ hbuf, const float* __restrict__ w_d,
    const int* __restrict__ ntiles, const int* __restrict__ tile_e,
    const int* __restrict__ tile_s0, const int* __restrict__ tile_n,
    unsigned short* __restrict__ ybuf) {
  int mt = blockIdx.x;
  if (mt >= *ntiles) return;
  int e = tile_e[mt], s0 = tile_s0[mt], nrows = tile_n[mt];
  int n0 = blockIdx.y * 64;
  __shared__ float As[BK][68];
  __shared__ float Bs[BK][68];
  int tid = threadIdx.x;
  int row = tid >> 2, kq = (tid & 3) << 2;
  int srow = s0 + row; if (srow >= NSLOT) srow = NSLOT - 1;
  const unsigned short* ap = hbuf + (size_t)srow * HH + kq;
  const float* bp = w_d + ((size_t)e * DM + (size_t)(n0 + row)) * HH + kq;
  int ty = tid >> 4, tx = tid & 15;
  float acc[4][4] = {};
  for (int k0 = 0; k0 < HH; k0 += BK) {
    ushort4 av = *(const ushort4*)(ap + k0);
    float4 bv = *(const float4*)(bp + k0);
    __syncthreads();
    As[kq + 0][row] = bs2f(av.x); As[kq + 1][row] = bs2f(av.y);
    As[kq + 2][row] = bs2f(av.z); As[kq + 3][row] = bs2f(av.w);
    Bs[kq + 0][row] = bv.x; Bs[kq + 1][row] = bv.y; Bs[kq + 2][row] = bv.z; Bs[kq + 3][row] = bv.w;
    __syncthreads();
#pragma unroll
    for (int kk = 0; kk < BK; ++kk) {
      float4 a4 = *(const float4*)&As[kk][ty * 4];
      float4 b4 = *(const float4*)&Bs[kk][tx * 4];
      float aa[4] = {a4.x, a4.y, a4.z, a4.w};
      float bb[4] = {b4.x, b4.y, b4.z, b4.w};
#pragma unroll
      for (int i = 0; i < 4; ++i)
#pragma unroll
        for (int j = 0; j < 4; ++j) acc[i][j] += aa[i] * bb[j];
    }
  }
#pragma unroll
  for (int i = 0; i < 4; ++i) {
    int r = ty * 4 + i;
    if (r < nrows) {
      ushort4 pk;
      pk.x = f2bs(acc[i][0]); pk.y = f2bs(acc[i][1]);
      pk.z = f2bs(acc[i][2]); pk.w = f2bs(acc[i][3]);
      *(ushort4*)(ybuf + ((size_t)(s0 + r) * DM + n0 + tx * 4)) = pk;
    }
  }
}

// ---------- K6: combine — out[t] = g1*y[slot1] + g2*y[slot2] ----------
__global__ __launch_bounds__(256) void k_combine(
    const unsigned short* __restrict__ ybuf, const int* __restrict__ t2s,
    const float* __restrict__ gval, float* __restrict__ out) {
  int gid = blockIdx.x * 256 + threadIdx.x;
  int t = gid >> 8;           // 256 float4's per token (D=1024)
  int d0 = (gid & 255) << 2;
  int s1 = t2s[t * 2], s2 = t2s[t * 2 + 1];
  float g1 = gval[t * 2], g2 = gval[t * 2 + 1];
  ushort4 y1 = *(const ushort4*)(ybuf + (size_t)s1 * DM + d0);
  ushort4 y2 = *(const ushort4*)(ybuf + (size_t)s2 * DM + d0);
  float4 o;
  o.x = g1 * bs2f(y1.x) + g2 * bs2f(y2.x);
  o.y = g1 * bs2f(y1.y) + g2 * bs2f(y2.y);
  o.z = g1 * bs2f(y1.z) + g2 * bs2f(y2.z);
  o.w = g1 * bs2f(y1.w) + g2 * bs2f(y2.w);
  *(float4*)(out + (size_t)t * DM + d0) = o;
}

// ---------- launcher ----------
extern "C" void kernel_launch(void* const* d_in, const int* in_sizes, int n_in,
                              void* d_out, int out_size, void* d_ws, size_t ws_size,
                              hipStream_t stream) {
  const float* x      = (const float*)d_in[0];
  const float* w_gate = (const float*)d_in[1];
  // d_in[2] = w_noise — unused in eval mode
  const float* w_g    = (const float*)d_in[3];
  const float* w_u    = (const float*)d_in[4];
  const float* w_d    = (const float*)d_in[5];
  float* out = (float*)d_out;

  char* ws = (char*)d_ws;
  int*   counts  = (int*)(ws + 0);       // [8]  zeroed
  int*   cursor  = (int*)(ws + 32);      // [8]  zeroed
  float* gsum    = (float*)(ws + 64);    // [8]  zeroed
  float* psum    = (float*)(ws + 96);    // [8]  zeroed
  int*   ntiles  = (int*)(ws + 128);
  int*   bases   = (int*)(ws + 160);     // [8]
  int*   tile_e  = (int*)(ws + 256);     // [160]
  int*   tile_s0 = (int*)(ws + 896);
  int*   tile_n  = (int*)(ws + 1536);
  int*   gidx    = (int*)(ws + 4096);    // [TT*2]
  float* gval    = (float*)(ws + 36864); // [TT*2]
  int*   stok    = (int*)(ws + 69632);   // [NSLOT]
  int*   t2s     = (int*)(ws + 102400);  // [TT*2]
  unsigned short* hbuf = (unsigned short*)(ws + 262144);                         // bf16 [NSLOT*HH] = 64 MiB
  unsigned short* ybuf = (unsigned short*)(ws + 262144 + (size_t)NSLOT * HH * 2); // bf16 [NSLOT*DM] = 16 MiB

  hipMemsetAsync(ws, 0, 256, stream);
  k_gate<<<256, 256, 0, stream>>>(x, w_gate, counts, gsum, psum, gidx, gval);
  k_plan<<<1, 64, 0, stream>>>(counts, gsum, psum, bases, ntiles, tile_e, tile_s0,
                               tile_n, out + (size_t)TT * DM);
  k_scatter<<<TT / 256, 256, 0, stream>>>(gidx, bases, cursor, stok, t2s);
  k_ffn1<<<dim3(MAXTILES, HH / 64), 256, 0, stream>>>(x, w_g, w_u, ntiles, tile_e,
                                                      tile_s0, tile_n, stok, hbuf);
  k_ffn2<<<dim3(MAXTILES, DM / 64), 256, 0, stream>>>(hbuf, w_d, ntiles, tile_e,
                                                      tile_s0, tile_n, ybuf);
  k_combine<<<(TT * DM / 4) / 256, 256, 0, stream>>>(ybuf, t2s, gval, out);
}

// Round 2
// 938.561 us; speedup vs baseline: 3.1246x; 3.1246x over previous
//
#include <hip/hip_runtime.h>

#define TT 4096      // tokens (B*S)
#define DM 1024      // d_model
#define HH 4096      // hidden
#define NE 8         // experts
#define NSLOT (TT*2) // total routed slots (always T*K)
#define TM 128       // M tile (slots)
#define MAXTILES 72  // sum ceil(c_e/128) <= 64+8

typedef __bf16 bf16x8 __attribute__((ext_vector_type(8)));
typedef float f32x4 __attribute__((ext_vector_type(4)));

// ---------- bf16 helpers ----------
__device__ __forceinline__ unsigned short f2bs(float f) {   // round-nearest
  unsigned u = __float_as_uint(f);
  u += 0x7fffu + ((u >> 16) & 1u);
  return (unsigned short)(u >> 16);
}
__device__ __forceinline__ float bs2f(unsigned short s) {
  return __uint_as_float(((unsigned)s) << 16);
}
// pack two floats -> two bf16 (round-half-up, 5 VALU ops)
__device__ __forceinline__ unsigned pk_rnd(float lo, float hi) {
  return ((__float_as_uint(lo) + 0x8000u) >> 16) |
         ((__float_as_uint(hi) + 0x8000u) & 0xffff0000u);
}
// global(16B/lane) -> LDS, wave-uniform lds base + lane*16
__device__ __forceinline__ void gld_lds16(const unsigned short* g, unsigned short* l) {
  __builtin_amdgcn_global_load_lds(
      (const __attribute__((address_space(1))) unsigned int*)g,
      (__attribute__((address_space(3))) unsigned int*)l, 16, 0, 0);
}

// ---------- K1: gating (logits, top-2, softmax, aux sums, counts) ----------
__global__ __launch_bounds__(256) void k_gate(
    const float* __restrict__ x, const float* __restrict__ w_gate,
    int* __restrict__ counts, float* __restrict__ gsum, float* __restrict__ psum,
    int* __restrict__ gidx, float* __restrict__ gval) {
  __shared__ float wg[NE * DM];
  __shared__ float bg[NE]; __shared__ float bp[NE]; __shared__ int bc[NE];
  int tid = threadIdx.x;
  for (int i = tid; i < NE * DM; i += 256) wg[i] = w_gate[i];
  if (tid < NE) { bg[tid] = 0.f; bp[tid] = 0.f; bc[tid] = 0; }
  __syncthreads();
  int wave = tid >> 6, lane = tid & 63;
  for (int it = 0; it < 4; ++it) {
    int t = blockIdx.x * 16 + wave * 4 + it;
    const float* xr = x + (size_t)t * DM;
    float s[NE];
#pragma unroll
    for (int e = 0; e < NE; ++e) s[e] = 0.f;
    for (int d = lane; d < DM; d += 64) {
      float xv = xr[d];
#pragma unroll
      for (int e = 0; e < NE; ++e) s[e] += xv * wg[e * DM + d];
    }
#pragma unroll
    for (int e = 0; e < NE; ++e) {
      float v = s[e];
      v += __shfl_down(v, 32); v += __shfl_down(v, 16); v += __shfl_down(v, 8);
      v += __shfl_down(v, 4);  v += __shfl_down(v, 2);  v += __shfl_down(v, 1);
      s[e] = v;
    }
    if (lane == 0) {
      int e1 = 0; float v1 = s[0];
      for (int e = 1; e < NE; ++e) if (s[e] > v1) { v1 = s[e]; e1 = e; }
      int e2 = -1; float v2 = -1e30f;
      for (int e = 0; e < NE; ++e) if (e != e1 && s[e] > v2) { v2 = s[e]; e2 = e; }
      float g1 = 1.f / (1.f + __expf(v2 - v1));
      float g2 = 1.f - g1;
      float psm = 0.f, p[NE];
      for (int e = 0; e < NE; ++e) { p[e] = __expf(s[e] - v1); psm += p[e]; }
      float inv = 1.f / psm;
      atomicAdd(&bg[e1], g1); atomicAdd(&bg[e2], g2);
      for (int e = 0; e < NE; ++e) atomicAdd(&bp[e], p[e] * inv);
      atomicAdd(&bc[e1], 1); atomicAdd(&bc[e2], 1);
      gidx[t * 2] = e1; gidx[t * 2 + 1] = e2;
      gval[t * 2] = g1; gval[t * 2 + 1] = g2;
    }
  }
  __syncthreads();
  if (tid < NE) {
    atomicAdd(&counts[tid], bc[tid]);
    atomicAdd(&gsum[tid], bg[tid]);
    atomicAdd(&psum[tid], bp[tid]);
  }
}

// ---------- K2: plan (prefix sum, tile table, aux loss) ----------
__global__ void k_plan(const int* __restrict__ counts, const float* __restrict__ gsum,
                       const float* __restrict__ psum, int* __restrict__ bases,
                       int* __restrict__ ntiles, int* __restrict__ tile_e,
                       int* __restrict__ tile_s0, int* __restrict__ tile_n,
                       float* __restrict__ aux_out) {
  if (threadIdx.x != 0 || blockIdx.x != 0) return;
  int base = 0, nt = 0;
  for (int e = 0; e < NE; ++e) {
    bases[e] = base;
    int c = counts[e];
    for (int s = 0; s < c; s += TM) {
      tile_e[nt] = e; tile_s0[nt] = base + s;
      tile_n[nt] = (c - s < TM) ? (c - s) : TM; ++nt;
    }
    base += c;
  }
  *ntiles = nt;
  float aux = 0.f;
  for (int e = 0; e < NE; ++e)
    aux += (gsum[e] / (float)TT) * (psum[e] / (float)TT);
  *aux_out = aux * (float)NE;
}

// ---------- K3: scatter tokens into expert-grouped slot lists ----------
__global__ __launch_bounds__(256) void k_scatter(
    const int* __restrict__ gidx, const int* __restrict__ bases,
    int* __restrict__ cursor, int* __restrict__ stok, int* __restrict__ t2s) {
  int t = blockIdx.x * 256 + threadIdx.x;
#pragma unroll
  for (int k = 0; k < 2; ++k) {
    int e = gidx[t * 2 + k];
    int pos = atomicAdd(&cursor[e], 1);
    int slot = bases[e] + pos;
    stok[slot] = t;
    t2s[t * 2 + k] = slot;
  }
}

// ---------- K4: gather + fp32->bf16: abuf[slot][d] = bf16(x[stok[slot]][d]) ----------
__global__ __launch_bounds__(256) void k_gather(
    const float* __restrict__ x, const int* __restrict__ stok,
    unsigned short* __restrict__ abuf) {
  int gid = blockIdx.x * 256 + threadIdx.x;   // NSLOT*128 threads, 8 elems each
  int slot = gid >> 7;
  int d0 = (gid & 127) << 3;
  int tok = stok[slot];
  const float* src = x + (size_t)tok * DM + d0;
  float4 v0 = *(const float4*)src;
  float4 v1 = *(const float4*)(src + 4);
  uint4 pk;
  pk.x = pk_rnd(v0.x, v0.y); pk.y = pk_rnd(v0.z, v0.w);
  pk.z = pk_rnd(v1.x, v1.y); pk.w = pk_rnd(v1.z, v1.w);
  *(uint4*)(abuf + (size_t)slot * DM + d0) = pk;
}

// ---------- K5: MFMA grouped GEMM1 — h = silu(A Wg^T) * (A Wu^T) ----------
// tile 128(M) x 64(N), BK=32; A bf16 via global_load_lds; B fp32 inline-cvt.
__global__ __launch_bounds__(256) void k_ffn1(
    const unsigned short* __restrict__ abuf, const float* __restrict__ w_g,
    const float* __restrict__ w_u, const int* __restrict__ ntiles,
    const int* __restrict__ tile_e, const int* __restrict__ tile_s0,
    const int* __restrict__ tile_n, unsigned short* __restrict__ hbuf) {
  int mt = blockIdx.x;
  if (mt >= *ntiles) return;
  int e = tile_e[mt], s0 = tile_s0[mt], nrows = tile_n[mt];
  int n0 = blockIdx.y * 64;
  __shared__ unsigned short As[TM * 32];   // 8 KB
  __shared__ unsigned short Bg[64 * 32];   // 4 KB
  __shared__ unsigned short Bu[64 * 32];   // 4 KB
  int tid = threadIdx.x, wid = tid >> 6, lane = tid & 63;
  int wm = (wid >> 1) * 64, wn = (wid & 1) * 32;
  int l15 = lane & 15, lq = lane >> 4;

  // A staging: wave wid covers rows [wid*32, wid*32+32), 2 issues of 16 rows
  const unsigned short* ap =
      abuf + (size_t)(s0 + wid * 32 + (lane >> 2)) * DM + (lane & 3) * 8;
  unsigned short* al0 = As + (wid * 32) * 32;
  unsigned short* al1 = As + (wid * 32 + 16) * 32;

  // B staging: thread stages 8 elems of each of Bg/Bu: row nb, cols k8..k8+7
  int nb = tid >> 2, k8 = (tid & 3) << 3;
  const float* gp = w_g + ((size_t)e * HH + (size_t)(n0 + nb)) * DM + k8;
  const float* up = w_u + ((size_t)e * HH + (size_t)(n0 + nb)) * DM + k8;
  unsigned short* bgl = Bg + nb * 32 + k8;
  unsigned short* bul = Bu + nb * 32 + k8;

  f32x4 accg[4][2], accu[4][2];
#pragma unroll
  for (int i = 0; i < 4; ++i)
#pragma unroll
    for (int j = 0; j < 2; ++j) {
      accg[i][j] = (f32x4){0.f, 0.f, 0.f, 0.f};
      accu[i][j] = (f32x4){0.f, 0.f, 0.f, 0.f};
    }

  for (int kb = 0; kb < DM; kb += 32) {
    __syncthreads();
    gld_lds16(ap + kb, al0);
    gld_lds16(ap + kb + 16 * DM, al1);
    float4 g0 = *(const float4*)(gp + kb);
    float4 g1 = *(const float4*)(gp + kb + 4);
    float4 u0 = *(const float4*)(up + kb);
    float4 u1 = *(const float4*)(up + kb + 4);
    uint4 pg, pu;
    pg.x = pk_rnd(g0.x, g0.y); pg.y = pk_rnd(g0.z, g0.w);
    pg.z = pk_rnd(g1.x, g1.y); pg.w = pk_rnd(g1.z, g1.w);
    pu.x = pk_rnd(u0.x, u0.y); pu.y = pk_rnd(u0.z, u0.w);
    pu.z = pk_rnd(u1.x, u1.y); pu.w = pk_rnd(u1.z, u1.w);
    *(uint4*)bgl = pg;
    *(uint4*)bul = pu;
    __syncthreads();
    bf16x8 af[4], bgf[2], buf_[2];
#pragma unroll
    for (int mi = 0; mi < 4; ++mi)
      af[mi] = *(const bf16x8*)&As[(wm + mi * 16 + l15) * 32 + lq * 8];
#pragma unroll
    for (int ni = 0; ni < 2; ++ni) {
      bgf[ni] = *(const bf16x8*)&Bg[(wn + ni * 16 + l15) * 32 + lq * 8];
      buf_[ni] = *(const bf16x8*)&Bu[(wn + ni * 16 + l15) * 32 + lq * 8];
    }
#pragma unroll
    for (int mi = 0; mi < 4; ++mi)
#pragma unroll
      for (int ni = 0; ni < 2; ++ni) {
        accg[mi][ni] = __builtin_amdgcn_mfma_f32_16x16x32_bf16(
            af[mi], bgf[ni], accg[mi][ni], 0, 0, 0);
        accu[mi][ni] = __builtin_amdgcn_mfma_f32_16x16x32_bf16(
            af[mi], buf_[ni], accu[mi][ni], 0, 0, 0);
      }
  }

  // epilogue: C lane map col=lane&15, row=lq*4+r
#pragma unroll
  for (int mi = 0; mi < 4; ++mi)
#pragma unroll
    for (int r = 0; r < 4; ++r) {
      int m_loc = wm + mi * 16 + lq * 4 + r;
      if (m_loc < nrows) {
#pragma unroll
        for (int ni = 0; ni < 2; ++ni) {
          float g = accg[mi][ni][r], u = accu[mi][ni][r];
          float h = g / (1.f + __expf(-g)) * u;
          int n = n0 + wn + ni * 16 + l15;
          hbuf[(size_t)(s0 + m_loc) * HH + n] = f2bs(h);
        }
      }
    }
}

// ---------- K6: MFMA grouped GEMM2 — y = h Wd^T ----------
__global__ __launch_bounds__(256) void k_ffn2(
    const unsigned short* __restrict__ hbuf, const float* __restrict__ w_d,
    const int* __restrict__ ntiles, const int* __restrict__ tile_e,
    const int* __restrict__ tile_s0, const int* __restrict__ tile_n,
    unsigned short* __restrict__ ybuf) {
  int mt = blockIdx.x;
  if (mt >= *ntiles) return;
  int e = tile_e[mt], s0 = tile_s0[mt], nrows = tile_n[mt];
  int n0 = blockIdx.y * 64;
  __shared__ unsigned short As[TM * 32];   // 8 KB
  __shared__ unsigned short Bs[64 * 32];   // 4 KB
  int tid = threadIdx.x, wid = tid >> 6, lane = tid & 63;
  int wm = (wid >> 1) * 64, wn = (wid & 1) * 32;
  int l15 = lane & 15, lq = lane >> 4;

  const unsigned short* ap =
      hbuf + (size_t)(s0 + wid * 32 + (lane >> 2)) * HH + (lane & 3) * 8;
  unsigned short* al0 = As + (wid * 32) * 32;
  unsigned short* al1 = As + (wid * 32 + 16) * 32;

  int nb = tid >> 2, k8 = (tid & 3) << 3;
  const float* dp = w_d + ((size_t)e * DM + (size_t)(n0 + nb)) * HH + k8;
  unsigned short* bl = Bs + nb * 32 + k8;

  f32x4 acc[4][2];
#pragma unroll
  for (int i = 0; i < 4; ++i)
#pragma unroll
    for (int j = 0; j < 2; ++j) acc[i][j] = (f32x4){0.f, 0.f, 0.f, 0.f};

  for (int kb = 0; kb < HH; kb += 32) {
    __syncthreads();
    gld_lds16(ap + kb, al0);
    gld_lds16(ap + kb + 16 * HH, al1);
    float4 d0 = *(const float4*)(dp + kb);
    float4 d1 = *(const float4*)(dp + kb + 4);
    uint4 pd;
    pd.x = pk_rnd(d0.x, d0.y); pd.y = pk_rnd(d0.z, d0.w);
    pd.z = pk_rnd(d1.x, d1.y); pd.w = pk_rnd(d1.z, d1.w);
    *(uint4*)bl = pd;
    __syncthreads();
    bf16x8 af[4], bf[2];
#pragma unroll
    for (int mi = 0; mi < 4; ++mi)
      af[mi] = *(const bf16x8*)&As[(wm + mi * 16 + l15) * 32 + lq * 8];
#pragma unroll
    for (int ni = 0; ni < 2; ++ni)
      bf[ni] = *(const bf16x8*)&Bs[(wn + ni * 16 + l15) * 32 + lq * 8];
#pragma unroll
    for (int mi = 0; mi < 4; ++mi)
#pragma unroll
      for (int ni = 0; ni < 2; ++ni)
        acc[mi][ni] = __builtin_amdgcn_mfma_f32_16x16x32_bf16(
            af[mi], bf[ni], acc[mi][ni], 0, 0, 0);
  }

#pragma unroll
  for (int mi = 0; mi < 4; ++mi)
#pragma unroll
    for (int r = 0; r < 4; ++r) {
      int m_loc = wm + mi * 16 + lq * 4 + r;
      if (m_loc < nrows) {
#pragma unroll
        for (int ni = 0; ni < 2; ++ni) {
          int n = n0 + wn + ni * 16 + l15;
          ybuf[(size_t)(s0 + m_loc) * DM + n] = f2bs(acc[mi][ni][r]);
        }
      }
    }
}

// ---------- K7: combine — out[t] = g1*y[slot1] + g2*y[slot2] ----------
__global__ __launch_bounds__(256) void k_combine(
    const unsigned short* __restrict__ ybuf, const int* __restrict__ t2s,
    const float* __restrict__ gval, float* __restrict__ out) {
  int gid = blockIdx.x * 256 + threadIdx.x;
  int t = gid >> 8;           // 256 float4's per token (D=1024)
  int d0 = (gid & 255) << 2;
  int s1 = t2s[t * 2], s2 = t2s[t * 2 + 1];
  float g1 = gval[t * 2], g2 = gval[t * 2 + 1];
  ushort4 y1 = *(const ushort4*)(ybuf + (size_t)s1 * DM + d0);
  ushort4 y2 = *(const ushort4*)(ybuf + (size_t)s2 * DM + d0);
  float4 o;
  o.x = g1 * bs2f(y1.x) + g2 * bs2f(y2.x);
  o.y = g1 * bs2f(y1.y) + g2 * bs2f(y2.y);
  o.z = g1 * bs2f(y1.z) + g2 * bs2f(y2.z);
  o.w = g1 * bs2f(y1.w) + g2 * bs2f(y2.w);
  *(float4*)(out + (size_t)t * DM + d0) = o;
}

// ---------- launcher ----------
extern "C" void kernel_launch(void* const* d_in, const int* in_sizes, int n_in,
                              void* d_out, int out_size, void* d_ws, size_t ws_size,
                              hipStream_t stream) {
  const float* x      = (const float*)d_in[0];
  const float* w_gate = (const float*)d_in[1];
  // d_in[2] = w_noise — unused in eval mode
  const float* w_g    = (const float*)d_in[3];
  const float* w_u    = (const float*)d_in[4];
  const float* w_d    = (const float*)d_in[5];
  float* out = (float*)d_out;

  char* ws = (char*)d_ws;
  int*   counts  = (int*)(ws + 0);       // zeroed
  int*   cursor  = (int*)(ws + 32);      // zeroed
  float* gsum    = (float*)(ws + 64);    // zeroed
  float* psum    = (float*)(ws + 96);    // zeroed
  int*   ntiles  = (int*)(ws + 128);
  int*   bases   = (int*)(ws + 192);
  int*   tile_e  = (int*)(ws + 4096);
  int*   tile_s0 = (int*)(ws + 4608);
  int*   tile_n  = (int*)(ws + 5120);
  int*   gidx    = (int*)(ws + 16384);
  float* gval    = (float*)(ws + 49152);
  int*   stok    = (int*)(ws + 81920);
  int*   t2s     = (int*)(ws + 114688);
  // abuf: NSLOT*DM bf16 = 16 MiB (+127-row slack); ybuf aliases abuf (ffn1 done first)
  unsigned short* abuf = (unsigned short*)(ws + (1 << 20));
  unsigned short* ybuf = abuf;
  // hbuf: NSLOT*HH bf16 = 64 MiB (+127-row slack) -> total ws use ~83 MiB
  unsigned short* hbuf = (unsigned short*)(ws + 18874368);

  hipMemsetAsync(ws, 0, 256, stream);
  k_gate<<<256, 256, 0, stream>>>(x, w_gate, counts, gsum, psum, gidx, gval);
  k_plan<<<1, 64, 0, stream>>>(counts, gsum, psum, bases, ntiles, tile_e, tile_s0,
                               tile_n, out + (size_t)TT * DM);
  k_scatter<<<TT / 256, 256, 0, stream>>>(gidx, bases, cursor, stok, t2s);
  k_gather<<<NSLOT * 128 / 256, 256, 0, stream>>>(x, stok, abuf);
  k_ffn1<<<dim3(MAXTILES, HH / 64), 256, 0, stream>>>(abuf, w_g, w_u, ntiles,
                                                      tile_e, tile_s0, tile_n, hbuf);
  k_ffn2<<<dim3(MAXTILES, DM / 64), 256, 0, stream>>>(hbuf, w_d, ntiles, tile_e,
                                                      tile_s0, tile_n, ybuf);
  k_combine<<<(TT * DM / 4) / 256, 256, 0, stream>>>(ybuf, t2s, gval, out);
}

// Round 3
// 833.510 us; speedup vs baseline: 3.5184x; 1.1260x over previous
//
#include <hip/hip_runtime.h>

#define TT 4096      // tokens (B*S)
#define DM 1024      // d_model
#define HH 4096      // hidden
#define NE 8         // experts
#define NSLOT (TT*2) // total routed slots (always T*K)
#define TM 128       // M tile (slots)
#define MAXTILES 72  // sum ceil(c_e/128) <= 64+8

typedef __bf16 bf16x8 __attribute__((ext_vector_type(8)));
typedef float f32x4 __attribute__((ext_vector_type(4)));

// ---------- bf16 helpers ----------
__device__ __forceinline__ unsigned short f2bs(float f) {   // RNE
  unsigned u = __float_as_uint(f);
  u += 0x7fffu + ((u >> 16) & 1u);
  return (unsigned short)(u >> 16);
}
__device__ __forceinline__ float bs2f(unsigned short s) {
  return __uint_as_float(((unsigned)s) << 16);
}
// pack two floats -> two bf16 (round-half-up)
__device__ __forceinline__ unsigned pk_rnd(float lo, float hi) {
  return ((__float_as_uint(lo) + 0x8000u) >> 16) |
         ((__float_as_uint(hi) + 0x8000u) & 0xffff0000u);
}
// global(16B/lane) -> LDS, wave-uniform lds base + lane*16
__device__ __forceinline__ void gld_lds16(const unsigned short* g, unsigned short* l) {
  __builtin_amdgcn_global_load_lds(
      (const __attribute__((address_space(1))) unsigned int*)g,
      (__attribute__((address_space(3))) unsigned int*)l, 16, 0, 0);
}

// ---------- K1: gating ----------
__global__ __launch_bounds__(256) void k_gate(
    const float* __restrict__ x, const float* __restrict__ w_gate,
    int* __restrict__ counts, float* __restrict__ gsum, float* __restrict__ psum,
    int* __restrict__ gidx, float* __restrict__ gval) {
  __shared__ float wg[NE * DM];
  __shared__ float bg[NE]; __shared__ float bp[NE]; __shared__ int bc[NE];
  int tid = threadIdx.x;
  for (int i = tid; i < NE * DM; i += 256) wg[i] = w_gate[i];
  if (tid < NE) { bg[tid] = 0.f; bp[tid] = 0.f; bc[tid] = 0; }
  __syncthreads();
  int wave = tid >> 6, lane = tid & 63;
  for (int it = 0; it < 4; ++it) {
    int t = blockIdx.x * 16 + wave * 4 + it;
    const float* xr = x + (size_t)t * DM;
    float s[NE];
#pragma unroll
    for (int e = 0; e < NE; ++e) s[e] = 0.f;
    for (int d = lane; d < DM; d += 64) {
      float xv = xr[d];
#pragma unroll
      for (int e = 0; e < NE; ++e) s[e] += xv * wg[e * DM + d];
    }
#pragma unroll
    for (int e = 0; e < NE; ++e) {
      float v = s[e];
      v += __shfl_down(v, 32); v += __shfl_down(v, 16); v += __shfl_down(v, 8);
      v += __shfl_down(v, 4);  v += __shfl_down(v, 2);  v += __shfl_down(v, 1);
      s[e] = v;
    }
    if (lane == 0) {
      int e1 = 0; float v1 = s[0];
      for (int e = 1; e < NE; ++e) if (s[e] > v1) { v1 = s[e]; e1 = e; }
      int e2 = -1; float v2 = -1e30f;
      for (int e = 0; e < NE; ++e) if (e != e1 && s[e] > v2) { v2 = s[e]; e2 = e; }
      float g1 = 1.f / (1.f + __expf(v2 - v1));
      float g2 = 1.f - g1;
      float psm = 0.f, p[NE];
      for (int e = 0; e < NE; ++e) { p[e] = __expf(s[e] - v1); psm += p[e]; }
      float inv = 1.f / psm;
      atomicAdd(&bg[e1], g1); atomicAdd(&bg[e2], g2);
      for (int e = 0; e < NE; ++e) atomicAdd(&bp[e], p[e] * inv);
      atomicAdd(&bc[e1], 1); atomicAdd(&bc[e2], 1);
      gidx[t * 2] = e1; gidx[t * 2 + 1] = e2;
      gval[t * 2] = g1; gval[t * 2 + 1] = g2;
    }
  }
  __syncthreads();
  if (tid < NE) {
    atomicAdd(&counts[tid], bc[tid]);
    atomicAdd(&gsum[tid], bg[tid]);
    atomicAdd(&psum[tid], bp[tid]);
  }
}

// ---------- K2: plan ----------
__global__ void k_plan(const int* __restrict__ counts, const float* __restrict__ gsum,
                       const float* __restrict__ psum, int* __restrict__ bases,
                       int* __restrict__ ntiles, int* __restrict__ tile_e,
                       int* __restrict__ tile_s0, int* __restrict__ tile_n,
                       float* __restrict__ aux_out) {
  if (threadIdx.x != 0 || blockIdx.x != 0) return;
  int base = 0, nt = 0;
  for (int e = 0; e < NE; ++e) {
    bases[e] = base;
    int c = counts[e];
    for (int s = 0; s < c; s += TM) {
      tile_e[nt] = e; tile_s0[nt] = base + s;
      tile_n[nt] = (c - s < TM) ? (c - s) : TM; ++nt;
    }
    base += c;
  }
  *ntiles = nt;
  float aux = 0.f;
  for (int e = 0; e < NE; ++e)
    aux += (gsum[e] / (float)TT) * (psum[e] / (float)TT);
  *aux_out = aux * (float)NE;
}

// ---------- K3: scatter ----------
__global__ __launch_bounds__(256) void k_scatter(
    const int* __restrict__ gidx, const int* __restrict__ bases,
    int* __restrict__ cursor, int* __restrict__ stok, int* __restrict__ t2s) {
  int t = blockIdx.x * 256 + threadIdx.x;
#pragma unroll
  for (int k = 0; k < 2; ++k) {
    int e = gidx[t * 2 + k];
    int pos = atomicAdd(&cursor[e], 1);
    int slot = bases[e] + pos;
    stok[slot] = t;
    t2s[t * 2 + k] = slot;
  }
}

// ---------- K4: gather + fp32->bf16 ----------
__global__ __launch_bounds__(256) void k_gather(
    const float* __restrict__ x, const int* __restrict__ stok,
    unsigned short* __restrict__ abuf) {
  int gid = blockIdx.x * 256 + threadIdx.x;
  int slot = gid >> 7;
  int d0 = (gid & 127) << 3;
  int tok = stok[slot];
  const float* src = x + (size_t)tok * DM + d0;
  float4 v0 = *(const float4*)src;
  float4 v1 = *(const float4*)(src + 4);
  uint4 pk;
  pk.x = pk_rnd(v0.x, v0.y); pk.y = pk_rnd(v0.z, v0.w);
  pk.z = pk_rnd(v1.x, v1.y); pk.w = pk_rnd(v1.z, v1.w);
  *(uint4*)(abuf + (size_t)slot * DM + d0) = pk;
}

// ---------- K4b: fused weight fp32->bf16 (w_g, w_u, w_d; 2^22 x 8 elems each) ----------
__global__ __launch_bounds__(256) void k_wconv3(
    const float* __restrict__ a, const float* __restrict__ b, const float* __restrict__ c,
    unsigned short* __restrict__ da, unsigned short* __restrict__ db,
    unsigned short* __restrict__ dc) {
  int gid = blockIdx.x * 256 + threadIdx.x;
  int seg = gid >> 22;
  size_t idx = (size_t)(gid & 0x3fffff) * 8;
  const float* s = (seg == 0 ? a : seg == 1 ? b : c) + idx;
  unsigned short* d = (seg == 0 ? da : seg == 1 ? db : dc) + idx;
  float4 v0 = *(const float4*)s;
  float4 v1 = *(const float4*)(s + 4);
  uint4 pk;
  pk.x = pk_rnd(v0.x, v0.y); pk.y = pk_rnd(v0.z, v0.w);
  pk.z = pk_rnd(v1.x, v1.y); pk.w = pk_rnd(v1.z, v1.w);
  *(uint4*)d = pk;
}

// ========== PRE-CONVERTED (bf16 B) GEMMs ==========

// K5bf: h = silu(A Wg^T) * (A Wu^T). tile 128x64, BK=32, all staging via gld_lds16.
__global__ __launch_bounds__(256) void k_ffn1_bf(
    const unsigned short* __restrict__ abuf, const unsigned short* __restrict__ wgb,
    const unsigned short* __restrict__ wub, const int* __restrict__ ntiles,
    const int* __restrict__ tile_e, const int* __restrict__ tile_s0,
    const int* __restrict__ tile_n, unsigned short* __restrict__ hbuf) {
  int mt = blockIdx.x;
  if (mt >= *ntiles) return;
  int e = tile_e[mt], s0 = tile_s0[mt], nrows = tile_n[mt];
  int n0 = blockIdx.y * 64;
  __shared__ unsigned short As[TM * 32];   // 8 KB
  __shared__ unsigned short Bg[64 * 32];   // 4 KB
  __shared__ unsigned short Bu[64 * 32];   // 4 KB
  int tid = threadIdx.x, wid = tid >> 6, lane = tid & 63;
  int wm = (wid >> 1) * 64, wn = (wid & 1) * 32;
  int l15 = lane & 15, lq = lane >> 4;
  int lrow = lane >> 2, lcol = (lane & 3) << 3;

  const unsigned short* ap = abuf + (size_t)(s0 + wid * 32 + lrow) * DM + lcol;
  unsigned short* al0 = As + (wid * 32) * 32;
  unsigned short* al1 = As + (wid * 32 + 16) * 32;
  const unsigned short* bgp = wgb + ((size_t)e * HH + (size_t)(n0 + wid * 16 + lrow)) * DM + lcol;
  const unsigned short* bup = wub + ((size_t)e * HH + (size_t)(n0 + wid * 16 + lrow)) * DM + lcol;
  unsigned short* bgl = Bg + (wid * 16) * 32;
  unsigned short* bul = Bu + (wid * 16) * 32;

  f32x4 accg[4][2], accu[4][2];
#pragma unroll
  for (int i = 0; i < 4; ++i)
#pragma unroll
    for (int j = 0; j < 2; ++j) {
      accg[i][j] = (f32x4){0.f, 0.f, 0.f, 0.f};
      accu[i][j] = (f32x4){0.f, 0.f, 0.f, 0.f};
    }

  for (int kb = 0; kb < DM; kb += 32) {
    __syncthreads();
    gld_lds16(ap + kb, al0);
    gld_lds16(ap + kb + 16 * DM, al1);
    gld_lds16(bgp + kb, bgl);
    gld_lds16(bup + kb, bul);
    __syncthreads();
    bf16x8 af[4], bgf[2], buf_[2];
#pragma unroll
    for (int mi = 0; mi < 4; ++mi)
      af[mi] = *(const bf16x8*)&As[(wm + mi * 16 + l15) * 32 + lq * 8];
#pragma unroll
    for (int ni = 0; ni < 2; ++ni) {
      bgf[ni] = *(const bf16x8*)&Bg[(wn + ni * 16 + l15) * 32 + lq * 8];
      buf_[ni] = *(const bf16x8*)&Bu[(wn + ni * 16 + l15) * 32 + lq * 8];
    }
#pragma unroll
    for (int mi = 0; mi < 4; ++mi)
#pragma unroll
      for (int ni = 0; ni < 2; ++ni) {
        accg[mi][ni] = __builtin_amdgcn_mfma_f32_16x16x32_bf16(
            af[mi], bgf[ni], accg[mi][ni], 0, 0, 0);
        accu[mi][ni] = __builtin_amdgcn_mfma_f32_16x16x32_bf16(
            af[mi], buf_[ni], accu[mi][ni], 0, 0, 0);
      }
  }

#pragma unroll
  for (int mi = 0; mi < 4; ++mi)
#pragma unroll
    for (int r = 0; r < 4; ++r) {
      int m_loc = wm + mi * 16 + lq * 4 + r;
      if (m_loc < nrows) {
#pragma unroll
        for (int ni = 0; ni < 2; ++ni) {
          float g = accg[mi][ni][r], u = accu[mi][ni][r];
          float h = g / (1.f + __expf(-g)) * u;
          int n = n0 + wn + ni * 16 + l15;
          hbuf[(size_t)(s0 + m_loc) * HH + n] = f2bs(h);
        }
      }
    }
}

// K6bf: y = h Wd^T. tile 128x128, BK=32, all staging via gld_lds16.
__global__ __launch_bounds__(256) void k_ffn2_bf(
    const unsigned short* __restrict__ hbuf, const unsigned short* __restrict__ wdb,
    const int* __restrict__ ntiles, const int* __restrict__ tile_e,
    const int* __restrict__ tile_s0, const int* __restrict__ tile_n,
    unsigned short* __restrict__ ybuf) {
  int mt = blockIdx.x;
  if (mt >= *ntiles) return;
  int e = tile_e[mt], s0 = tile_s0[mt], nrows = tile_n[mt];
  int n0 = blockIdx.y * 128;
  __shared__ unsigned short As[TM * 32];    // 8 KB
  __shared__ unsigned short Bs[128 * 32];   // 8 KB
  int tid = threadIdx.x, wid = tid >> 6, lane = tid & 63;
  int wm = (wid >> 1) * 64, wn = (wid & 1) * 64;
  int l15 = lane & 15, lq = lane >> 4;
  int lrow = lane >> 2, lcol = (lane & 3) << 3;

  const unsigned short* ap = hbuf + (size_t)(s0 + wid * 32 + lrow) * HH + lcol;
  unsigned short* al0 = As + (wid * 32) * 32;
  unsigned short* al1 = As + (wid * 32 + 16) * 32;
  const unsigned short* bp = wdb + ((size_t)e * DM + (size_t)(n0 + wid * 32 + lrow)) * HH + lcol;
  unsigned short* bl0 = Bs + (wid * 32) * 32;
  unsigned short* bl1 = Bs + (wid * 32 + 16) * 32;

  f32x4 acc[4][4];
#pragma unroll
  for (int i = 0; i < 4; ++i)
#pragma unroll
    for (int j = 0; j < 4; ++j) acc[i][j] = (f32x4){0.f, 0.f, 0.f, 0.f};

  for (int kb = 0; kb < HH; kb += 32) {
    __syncthreads();
    gld_lds16(ap + kb, al0);
    gld_lds16(ap + kb + 16 * HH, al1);
    gld_lds16(bp + kb, bl0);
    gld_lds16(bp + kb + 16 * HH, bl1);
    __syncthreads();
    bf16x8 af[4], bf[4];
#pragma unroll
    for (int mi = 0; mi < 4; ++mi)
      af[mi] = *(const bf16x8*)&As[(wm + mi * 16 + l15) * 32 + lq * 8];
#pragma unroll
    for (int ni = 0; ni < 4; ++ni)
      bf[ni] = *(const bf16x8*)&Bs[(wn + ni * 16 + l15) * 32 + lq * 8];
#pragma unroll
    for (int mi = 0; mi < 4; ++mi)
#pragma unroll
      for (int ni = 0; ni < 4; ++ni)
        acc[mi][ni] = __builtin_amdgcn_mfma_f32_16x16x32_bf16(
            af[mi], bf[ni], acc[mi][ni], 0, 0, 0);
  }

#pragma unroll
  for (int mi = 0; mi < 4; ++mi)
#pragma unroll
    for (int r = 0; r < 4; ++r) {
      int m_loc = wm + mi * 16 + lq * 4 + r;
      if (m_loc < nrows) {
#pragma unroll
        for (int ni = 0; ni < 4; ++ni) {
          int n = n0 + wn + ni * 16 + l15;
          ybuf[(size_t)(s0 + m_loc) * DM + n] = f2bs(acc[mi][ni][r]);
        }
      }
    }
}

// ========== FALLBACK (fp32 B inline-convert) GEMMs — round-2 proven ==========

__global__ __launch_bounds__(256) void k_ffn1_f32(
    const unsigned short* __restrict__ abuf, const float* __restrict__ w_g,
    const float* __restrict__ w_u, const int* __restrict__ ntiles,
    const int* __restrict__ tile_e, const int* __restrict__ tile_s0,
    const int* __restrict__ tile_n, unsigned short* __restrict__ hbuf) {
  int mt = blockIdx.x;
  if (mt >= *ntiles) return;
  int e = tile_e[mt], s0 = tile_s0[mt], nrows = tile_n[mt];
  int n0 = blockIdx.y * 64;
  __shared__ unsigned short As[TM * 32];
  __shared__ unsigned short Bg[64 * 32];
  __shared__ unsigned short Bu[64 * 32];
  int tid = threadIdx.x, wid = tid >> 6, lane = tid & 63;
  int wm = (wid >> 1) * 64, wn = (wid & 1) * 32;
  int l15 = lane & 15, lq = lane >> 4;
  const unsigned short* ap =
      abuf + (size_t)(s0 + wid * 32 + (lane >> 2)) * DM + (lane & 3) * 8;
  unsigned short* al0 = As + (wid * 32) * 32;
  unsigned short* al1 = As + (wid * 32 + 16) * 32;
  int nb = tid >> 2, k8 = (tid & 3) << 3;
  const float* gp = w_g + ((size_t)e * HH + (size_t)(n0 + nb)) * DM + k8;
  const float* up = w_u + ((size_t)e * HH + (size_t)(n0 + nb)) * DM + k8;
  unsigned short* bgl = Bg + nb * 32 + k8;
  unsigned short* bul = Bu + nb * 32 + k8;
  f32x4 accg[4][2], accu[4][2];
#pragma unroll
  for (int i = 0; i < 4; ++i)
#pragma unroll
    for (int j = 0; j < 2; ++j) {
      accg[i][j] = (f32x4){0.f, 0.f, 0.f, 0.f};
      accu[i][j] = (f32x4){0.f, 0.f, 0.f, 0.f};
    }
  for (int kb = 0; kb < DM; kb += 32) {
    __syncthreads();
    gld_lds16(ap + kb, al0);
    gld_lds16(ap + kb + 16 * DM, al1);
    float4 g0 = *(const float4*)(gp + kb);
    float4 g1 = *(const float4*)(gp + kb + 4);
    float4 u0 = *(const float4*)(up + kb);
    float4 u1 = *(const float4*)(up + kb + 4);
    uint4 pg, pu;
    pg.x = pk_rnd(g0.x, g0.y); pg.y = pk_rnd(g0.z, g0.w);
    pg.z = pk_rnd(g1.x, g1.y); pg.w = pk_rnd(g1.z, g1.w);
    pu.x = pk_rnd(u0.x, u0.y); pu.y = pk_rnd(u0.z, u0.w);
    pu.z = pk_rnd(u1.x, u1.y); pu.w = pk_rnd(u1.z, u1.w);
    *(uint4*)bgl = pg;
    *(uint4*)bul = pu;
    __syncthreads();
    bf16x8 af[4], bgf[2], buf_[2];
#pragma unroll
    for (int mi = 0; mi < 4; ++mi)
      af[mi] = *(const bf16x8*)&As[(wm + mi * 16 + l15) * 32 + lq * 8];
#pragma unroll
    for (int ni = 0; ni < 2; ++ni) {
      bgf[ni] = *(const bf16x8*)&Bg[(wn + ni * 16 + l15) * 32 + lq * 8];
      buf_[ni] = *(const bf16x8*)&Bu[(wn + ni * 16 + l15) * 32 + lq * 8];
    }
#pragma unroll
    for (int mi = 0; mi < 4; ++mi)
#pragma unroll
      for (int ni = 0; ni < 2; ++ni) {
        accg[mi][ni] = __builtin_amdgcn_mfma_f32_16x16x32_bf16(
            af[mi], bgf[ni], accg[mi][ni], 0, 0, 0);
        accu[mi][ni] = __builtin_amdgcn_mfma_f32_16x16x32_bf16(
            af[mi], buf_[ni], accu[mi][ni], 0, 0, 0);
      }
  }
#pragma unroll
  for (int mi = 0; mi < 4; ++mi)
#pragma unroll
    for (int r = 0; r < 4; ++r) {
      int m_loc = wm + mi * 16 + lq * 4 + r;
      if (m_loc < nrows) {
#pragma unroll
        for (int ni = 0; ni < 2; ++ni) {
          float g = accg[mi][ni][r], u = accu[mi][ni][r];
          float h = g / (1.f + __expf(-g)) * u;
          int n = n0 + wn + ni * 16 + l15;
          hbuf[(size_t)(s0 + m_loc) * HH + n] = f2bs(h);
        }
      }
    }
}

__global__ __launch_bounds__(256) void k_ffn2_f32(
    const unsigned short* __restrict__ hbuf, const float* __restrict__ w_d,
    const int* __restrict__ ntiles, const int* __restrict__ tile_e,
    const int* __restrict__ tile_s0, const int* __restrict__ tile_n,
    unsigned short* __restrict__ ybuf) {
  int mt = blockIdx.x;
  if (mt >= *ntiles) return;
  int e = tile_e[mt], s0 = tile_s0[mt], nrows = tile_n[mt];
  int n0 = blockIdx.y * 64;
  __shared__ unsigned short As[TM * 32];
  __shared__ unsigned short Bs[64 * 32];
  int tid = threadIdx.x, wid = tid >> 6, lane = tid & 63;
  int wm = (wid >> 1) * 64, wn = (wid & 1) * 32;
  int l15 = lane & 15, lq = lane >> 4;
  const unsigned short* ap =
      hbuf + (size_t)(s0 + wid * 32 + (lane >> 2)) * HH + (lane & 3) * 8;
  unsigned short* al0 = As + (wid * 32) * 32;
  unsigned short* al1 = As + (wid * 32 + 16) * 32;
  int nb = tid >> 2, k8 = (tid & 3) << 3;
  const float* dp = w_d + ((size_t)e * DM + (size_t)(n0 + nb)) * HH + k8;
  unsigned short* bl = Bs + nb * 32 + k8;
  f32x4 acc[4][2];
#pragma unroll
  for (int i = 0; i < 4; ++i)
#pragma unroll
    for (int j = 0; j < 2; ++j) acc[i][j] = (f32x4){0.f, 0.f, 0.f, 0.f};
  for (int kb = 0; kb < HH; kb += 32) {
    __syncthreads();
    gld_lds16(ap + kb, al0);
    gld_lds16(ap + kb + 16 * HH, al1);
    float4 d0 = *(const float4*)(dp + kb);
    float4 d1 = *(const float4*)(dp + kb + 4);
    uint4 pd;
    pd.x = pk_rnd(d0.x, d0.y); pd.y = pk_rnd(d0.z, d0.w);
    pd.z = pk_rnd(d1.x, d1.y); pd.w = pk_rnd(d1.z, d1.w);
    *(uint4*)bl = pd;
    __syncthreads();
    bf16x8 af[4], bf[2];
#pragma unroll
    for (int mi = 0; mi < 4; ++mi)
      af[mi] = *(const bf16x8*)&As[(wm + mi * 16 + l15) * 32 + lq * 8];
#pragma unroll
    for (int ni = 0; ni < 2; ++ni)
      bf[ni] = *(const bf16x8*)&Bs[(wn + ni * 16 + l15) * 32 + lq * 8];
#pragma unroll
    for (int mi = 0; mi < 4; ++mi)
#pragma unroll
      for (int ni = 0; ni < 2; ++ni)
        acc[mi][ni] = __builtin_amdgcn_mfma_f32_16x16x32_bf16(
            af[mi], bf[ni], acc[mi][ni], 0, 0, 0);
  }
#pragma unroll
  for (int mi = 0; mi < 4; ++mi)
#pragma unroll
    for (int r = 0; r < 4; ++r) {
      int m_loc = wm + mi * 16 + lq * 4 + r;
      if (m_loc < nrows) {
#pragma unroll
        for (int ni = 0; ni < 2; ++ni) {
          int n = n0 + wn + ni * 16 + l15;
          ybuf[(size_t)(s0 + m_loc) * DM + n] = f2bs(acc[mi][ni][r]);
        }
      }
    }
}

// ---------- K7: combine ----------
__global__ __launch_bounds__(256) void k_combine(
    const unsigned short* __restrict__ ybuf, const int* __restrict__ t2s,
    const float* __restrict__ gval, float* __restrict__ out) {
  int gid = blockIdx.x * 256 + threadIdx.x;
  int t = gid >> 8;
  int d0 = (gid & 255) << 2;
  int s1 = t2s[t * 2], s2 = t2s[t * 2 + 1];
  float g1 = gval[t * 2], g2 = gval[t * 2 + 1];
  ushort4 y1 = *(const ushort4*)(ybuf + (size_t)s1 * DM + d0);
  ushort4 y2 = *(const ushort4*)(ybuf + (size_t)s2 * DM + d0);
  float4 o;
  o.x = g1 * bs2f(y1.x) + g2 * bs2f(y2.x);
  o.y = g1 * bs2f(y1.y) + g2 * bs2f(y2.y);
  o.z = g1 * bs2f(y1.z) + g2 * bs2f(y2.z);
  o.w = g1 * bs2f(y1.w) + g2 * bs2f(y2.w);
  *(float4*)(out + (size_t)t * DM + d0) = o;
}

// ---------- launcher ----------
extern "C" void kernel_launch(void* const* d_in, const int* in_sizes, int n_in,
                              void* d_out, int out_size, void* d_ws, size_t ws_size,
                              hipStream_t stream) {
  const float* x      = (const float*)d_in[0];
  const float* w_gate = (const float*)d_in[1];
  const float* w_g    = (const float*)d_in[3];
  const float* w_u    = (const float*)d_in[4];
  const float* w_d    = (const float*)d_in[5];
  float* out = (float*)d_out;

  char* ws = (char*)d_ws;
  int*   counts  = (int*)(ws + 0);
  int*   cursor  = (int*)(ws + 32);
  float* gsum    = (float*)(ws + 64);
  float* psum    = (float*)(ws + 96);
  int*   ntiles  = (int*)(ws + 128);
  int*   bases   = (int*)(ws + 192);
  int*   tile_e  = (int*)(ws + 4096);
  int*   tile_s0 = (int*)(ws + 4608);
  int*   tile_n  = (int*)(ws + 5120);
  int*   gidx    = (int*)(ws + 16384);
  float* gval    = (float*)(ws + 49152);
  int*   stok    = (int*)(ws + 81920);
  int*   t2s     = (int*)(ws + 114688);
  // abuf @1MB: 16MB (+0.5MB over-read slack); ybuf aliases abuf
  unsigned short* abuf = (unsigned short*)(ws + (1ull << 20));
  unsigned short* ybuf = abuf;
  // hbuf @18MB: 64MB (+1.5MB over-read slack)
  unsigned short* hbuf = (unsigned short*)(ws + (18ull << 20));
  // bf16 weights @84/148/212 MB (64MB each) -> full path needs 276MB
  unsigned short* wgb = (unsigned short*)(ws + (84ull << 20));
  unsigned short* wub = (unsigned short*)(ws + (148ull << 20));
  unsigned short* wdb = (unsigned short*)(ws + (212ull << 20));
  const bool pre = ws_size >= (277ull << 20);  // constant per-session -> same work every call

  hipMemsetAsync(ws, 0, 256, stream);
  k_gate<<<256, 256, 0, stream>>>(x, w_gate, counts, gsum, psum, gidx, gval);
  k_plan<<<1, 64, 0, stream>>>(counts, gsum, psum, bases, ntiles, tile_e, tile_s0,
                               tile_n, out + (size_t)TT * DM);
  k_scatter<<<TT / 256, 256, 0, stream>>>(gidx, bases, cursor, stok, t2s);
  k_gather<<<NSLOT * 128 / 256, 256, 0, stream>>>(x, stok, abuf);
  if (pre) {
    k_wconv3<<<3 * (NE * HH * DM / 8) / 256, 256, 0, stream>>>(w_g, w_u, w_d, wgb, wub, wdb);
    k_ffn1_bf<<<dim3(MAXTILES, HH / 64), 256, 0, stream>>>(abuf, wgb, wub, ntiles,
                                                           tile_e, tile_s0, tile_n, hbuf);
    k_ffn2_bf<<<dim3(MAXTILES, DM / 128), 256, 0, stream>>>(hbuf, wdb, ntiles, tile_e,
                                                            tile_s0, tile_n, ybuf);
  } else {
    k_ffn1_f32<<<dim3(MAXTILES, HH / 64), 256, 0, stream>>>(abuf, w_g, w_u, ntiles,
                                                            tile_e, tile_s0, tile_n, hbuf);
    k_ffn2_f32<<<dim3(MAXTILES, DM / 64), 256, 0, stream>>>(hbuf, w_d, ntiles, tile_e,
                                                            tile_s0, tile_n, ybuf);
  }
  k_combine<<<(TT * DM / 4) / 256, 256, 0, stream>>>(ybuf, t2s, gval, out);
}